// Round 7
// baseline (254.881 us; speedup 1.0000x reference)
//
#include <hip/hip_runtime.h>
#include <stdint.h>

typedef _Float16 f16;
typedef _Float16 f16x4 __attribute__((ext_vector_type(4)));
typedef _Float16 f16x8 __attribute__((ext_vector_type(8)));
typedef float f32x4 __attribute__((ext_vector_type(4)));

#define K_DIM 1600
#define NF_DIM 6400
#define KPAD 1664   // 26 tiles of 64
#define NKT 26
#define KPB (KPAD * 2)  // row stride bytes = 3328

// GEMM geometry: BM=128, BN=320, BK=64 -> 64x20 = 1280 tiles = 5/CU exact.
#define BUFSZ 57344   // A 16KB + B 40KB
#define BOFF 16384    // B region offset within buffer

// ---------- async global->LDS 16B copy ----------
__device__ __forceinline__ void async_copy16(const void* g, void* l) {
    __builtin_amdgcn_global_load_lds(
        (const __attribute__((address_space(1))) void*)(uintptr_t)g,
        (__attribute__((address_space(3))) void*)(uint32_t)(uintptr_t)l,
        16, 0, 0);
}

// ---------- block-wide max (256 threads = 4 waves) ----------
__device__ __forceinline__ float blockMax(float v, float* sm) {
#pragma unroll
    for (int off = 32; off > 0; off >>= 1)
        v = fmaxf(v, __shfl_down(v, off, 64));
    int wid = threadIdx.x >> 6, lane = threadIdx.x & 63;
    if (lane == 0) sm[wid] = v;
    __syncthreads();
    if (threadIdx.x == 0) {
        float m = sm[0];
        for (int i = 1; i < (int)(blockDim.x >> 6); ++i) m = fmaxf(m, sm[i]);
        sm[0] = m;
    }
    __syncthreads();
    return sm[0];
}

// ---------- per-token activation quant ----------
__global__ void quant_x_kernel(const float* __restrict__ x, f16* __restrict__ qx,
                               float* __restrict__ ax) {
    __shared__ float sm[4];
    size_t row = blockIdx.x;
    const float* xr = x + row * (size_t)K_DIM;
    float m = 0.f;
    const int n4 = K_DIM >> 2;
    for (int i = threadIdx.x; i < n4; i += blockDim.x) {
        float4 v = ((const float4*)xr)[i];
        m = fmaxf(fmaxf(fmaxf(fabsf(v.x), fabsf(v.y)), fmaxf(fabsf(v.z), fabsf(v.w))), m);
    }
    m = blockMax(m, sm);
    float s = 127.0f / (m + 1e-6f);
    if (threadIdx.x == 0) ax[row] = 1.0f / (s + 1e-6f);
    f16* qr = qx + row * (size_t)KPAD;
    for (int i = threadIdx.x; i < n4; i += blockDim.x) {
        float4 v = ((const float4*)xr)[i];
        f16x4 q;
        q[0] = (f16)rintf(v.x * s);
        q[1] = (f16)rintf(v.y * s);
        q[2] = (f16)rintf(v.z * s);
        q[3] = (f16)rintf(v.w * s);
        *(f16x4*)&qr[i * 4] = q;
    }
    if (threadIdx.x < 16) {
        f16x4 z = {};
        *(f16x4*)&qr[K_DIM + threadIdx.x * 4] = z;
    }
}

// ---------- per-row weight scale ----------
__global__ void wscale_kernel(const float* __restrict__ w, float* __restrict__ sw) {
    __shared__ float sm[4];
    size_t k = blockIdx.x;
    const float* wr = w + k * (size_t)NF_DIM;
    float m = 0.f;
    const int n4 = NF_DIM >> 2;
    for (int i = threadIdx.x; i < n4; i += blockDim.x) {
        float4 v = ((const float4*)wr)[i];
        m = fmaxf(fmaxf(fmaxf(fabsf(v.x), fabsf(v.y)), fmaxf(fabsf(v.z), fabsf(v.w))), m);
    }
    m = blockMax(m, sm);
    if (threadIdx.x == 0) sw[k] = 127.0f / (m + 1e-6f);
}

// ---------- quantize + transpose weight -> wqt[N][KPAD] fp16 ----------
__global__ void wtq_kernel(const float* __restrict__ w, const float* __restrict__ sw,
                           f16* __restrict__ wqt) {
    __shared__ f16 t[64][80];
    int k0 = blockIdx.x * 64;
    int f0 = blockIdx.y * 64;
    int tid = threadIdx.x;
    if (k0 >= K_DIM) {
        int fr = tid >> 2;
        int ch = (tid & 3) << 4;
        float4 z = {};
        float4* dst = (float4*)&wqt[(size_t)(f0 + fr) * KPAD + k0 + ch];
        dst[0] = z;
        dst[1] = z;
        return;
    }
    int rr = tid >> 4;
    int cc = (tid & 15) << 2;
#pragma unroll
    for (int i = 0; i < 4; ++i) {
        int r = rr + i * 16;
        float s = sw[k0 + r];
        float inv = 1.0f / (s + 1e-6f);
        float4 v = *(const float4*)&w[(size_t)(k0 + r) * NF_DIM + f0 + cc];
        t[cc + 0][r] = (f16)(rintf(v.x * s) * inv);
        t[cc + 1][r] = (f16)(rintf(v.y * s) * inv);
        t[cc + 2][r] = (f16)(rintf(v.z * s) * inv);
        t[cc + 3][r] = (f16)(rintf(v.w * s) * inv);
    }
    __syncthreads();
    int fr = tid >> 2;
    int ch = (tid & 3) << 4;
    const float4* src = (const float4*)&t[fr][ch];
    float4* dst = (float4*)&wqt[(size_t)(f0 + fr) * KPAD + k0 + ch];
    dst[0] = src[0];
    dst[1] = src[1];
}

// ---------- 128x320 GEMM, 4 phases/tile, 2 barriers/tile, counted lgkm ----------
__global__ __launch_bounds__(512, 1) void gemm128x320(
    const f16* __restrict__ A,    // [M][KPAD]
    const f16* __restrict__ Bt,   // [N][KPAD]
    const float* __restrict__ ax,
    const float* __restrict__ bias,
    float* __restrict__ C, int M, int N) {
    extern __shared__ char lds[];
    // buf b at lds + b*BUFSZ: A[128][64]f16 @+0, B[320][64]f16 @+16384

    const int tid = threadIdx.x;
    const int lane = tid & 63;
    const int wv = tid >> 6;   // 0..7
    const int wm = wv >> 2;    // 0..1 (64-row half)
    const int wn = wv & 3;     // 0..3 (80-col quarter)
    const int lr = lane & 15;
    const int lg = lane >> 4;

    const int bid = blockIdx.x;
    const int cpx = gridDim.x >> 3;     // 160 (1280 % 8 == 0 -> bijective)
    const int swz = (bid & 7) * cpx + (bid >> 3);
    const int tm = swz & 63;            // tn-major: consecutive swz share B panel
    const int tn = swz >> 6;
    const size_t m0 = (size_t)tm * 128, n0 = (size_t)tn * 320;

    // ---- staging pointers (inverse-swizzled source, linear LDS dest) ----
    const int srow8 = lane >> 3;
    const int sslot = (lane & 7) ^ srow8;
    const char* pA = (const char*)A + (m0 + (size_t)(wv * 8 + srow8)) * KPB + sslot * 16;
    const char* pB = (const char*)Bt + (n0 + (size_t)(wv * 8 + srow8)) * KPB + sslot * 16;
    const int L0 = wv * 1024 + lane * 16;

    // A tile: 2 calls (64 rows each); B tile: 5 calls
#define ST_A(bufo, t)                                                          \
    {                                                                          \
        const char* g_ = pA + (size_t)(t) * 128;                               \
        async_copy16(g_, lds + (bufo) + L0);                                   \
        async_copy16(g_ + (size_t)64 * KPB, lds + (bufo) + 8192 + L0);         \
    }
#define ST_B(bufo, t)                                                          \
    {                                                                          \
        const char* g_ = pB + (size_t)(t) * 128;                               \
        _Pragma("unroll") for (int c_ = 0; c_ < 5; ++c_)                       \
            async_copy16(g_ + (size_t)(c_ * 64) * KPB,                         \
                         lds + (bufo) + BOFF + c_ * 8192 + L0);                \
    }

    // ---- fragment-read constants (XOR swizzle folded per-thread) ----
    const int swz0 = ((lg) ^ (lr & 7)) << 4;       // kk=0 chunk
    const int swz1 = ((4 + lg) ^ (lr & 7)) << 4;   // kk=1 chunk
    const int rbA = (wm * 64 + lr) * 128;
    const int rbB = BOFF + wn * 10240 + lr * 128;

    // A piece: 2 frags (rows a*16 apart); rowoff: 0 = lo (a=0,1), 4096 = hi (a=2,3)
#define RD_A(dst, bufo, rowoff, sz)                                    \
    {                                                                  \
        const char* p_ = lds + (bufo) + rbA + (rowoff) + (sz);         \
        dst[0] = *(const f16x8*)(p_);                                  \
        dst[1] = *(const f16x8*)(p_ + 2048);                           \
    }
    // B set of one kk: 5 frags
#define RD_B(dst, bufo, sz)                                            \
    {                                                                  \
        const char* p_ = lds + (bufo) + rbB + (sz);                    \
        _Pragma("unroll") for (int n_ = 0; n_ < 5; ++n_)               \
            dst[n_] = *(const f16x8*)(p_ + n_ * 2048);                 \
    }

#define BARRIER __builtin_amdgcn_s_barrier()
#define LGKM(n) asm volatile("s_waitcnt lgkmcnt(" #n ")" ::: "memory")
#define VM0 asm volatile("s_waitcnt vmcnt(0)" ::: "memory")
#define SB0 __builtin_amdgcn_sched_barrier(0)

    // 10 MFMA: A piece (2 frags, rows R0*16..) x 5 B frags
#define MF25(AF, BF, R0)                                                          \
    {                                                                             \
        __builtin_amdgcn_s_setprio(1);                                            \
        _Pragma("unroll") for (int a_ = 0; a_ < 2; ++a_)                          \
        _Pragma("unroll") for (int n_ = 0; n_ < 5; ++n_)                          \
            acc[(R0) + a_][n_] = __builtin_amdgcn_mfma_f32_16x16x32_f16(          \
                AF[a_], BF[n_], acc[(R0) + a_][n_], 0, 0, 0);                     \
        __builtin_amdgcn_s_setprio(0);                                            \
    }

    // one tile: 4 phases, 2 barriers; CUR/NXT compile-time buffer offsets
    // lgkm ledger (FIFO): enter with 7 outstanding (prev PH4's reads)
#define TILE(CUR, NXT, tcur, tnext)                                   \
    {                                                                 \
        /* PH1: rd aN=A-lo-k1(2) + B1(5); stage A(t+1) */             \
        RD_A(aN, CUR, 0, swz1);                                       \
        RD_B(B1, CUR, swz1);                                          \
        ST_A(NXT, tnext);                                             \
        LGKM(7); SB0;               /* aP, B0 ready */                \
        MF25(aP, B0, 0);                                              \
        /* PH2: rd aP=A-hi-k0(2); stage B(t+1) */                     \
        RD_A(aP, CUR, 4096, swz0);                                    \
        ST_B(NXT, tnext);                                             \
        LGKM(2); SB0;               /* aN, B1 ready */                \
        MF25(aN, B1, 0);                                              \
        /* PH3: rd aN=A-hi-k1(2) */                                   \
        RD_A(aN, CUR, 4096, swz1);                                    \
        LGKM(2); SB0;               /* aP (A-hi-k0) ready */          \
        MF25(aP, B0, 2);                                              \
        /* PH4: drain staging; all-waves barrier; pre-read next */    \
        VM0;                                                          \
        BARRIER; SB0;               /* NXT fully landed */            \
        RD_A(aP, NXT, 0, swz0);                                       \
        RD_B(B0, NXT, swz0);                                          \
        LGKM(7); SB0;               /* aN (A-hi-k1) ready */          \
        MF25(aN, B1, 2);                                              \
        BARRIER;                    /* all reads of CUR executed */   \
    }

    f32x4 acc[4][5] = {};
    f16x8 aP[2], aN[2], B0[5], B1[5];

    // ---- prologue: stage tile0 -> buf0; pre-read PH1 operands ----
    ST_A(0, 0);
    ST_B(0, 0);
    VM0;
    BARRIER;
    RD_A(aP, 0, 0, swz0);   // A-lo-k0 (t0)
    RD_B(B0, 0, swz0);      // B-k0   (t0)  -> 7 lgkm outstanding

    for (int i = 0; i < NKT / 2; ++i) {
        const int te = 2 * i + 1;                                // stage idx during even tile
        const int to = (2 * i + 2 < NKT) ? 2 * i + 2 : NKT - 1;  // clamped during odd tile
        TILE(0, BUFSZ, 2 * i, te);
        TILE(BUFSZ, 0, 2 * i + 1, to);
    }
    asm volatile("s_waitcnt vmcnt(0) lgkmcnt(0)" ::: "memory");

    // ---- epilogue: direct stores, ax*acc + bias ----
    float bv[5];
#pragma unroll
    for (int n_ = 0; n_ < 5; ++n_) bv[n_] = bias[n0 + wn * 80 + n_ * 16 + lr];
#pragma unroll
    for (int a = 0; a < 4; ++a) {
#pragma unroll
        for (int j = 0; j < 4; ++j) {
            size_t row = m0 + wm * 64 + a * 16 + lg * 4 + j;
            float axv = ax[row];
            float* crow = C + row * (size_t)N + n0 + wn * 80;
#pragma unroll
            for (int n_ = 0; n_ < 5; ++n_)
                crow[n_ * 16 + lr] = acc[a][n_][j] * axv + bv[n_];
        }
    }
}

extern "C" void kernel_launch(void* const* d_in, const int* in_sizes, int n_in,
                              void* d_out, int out_size, void* d_ws, size_t ws_size,
                              hipStream_t stream) {
    const float* x = (const float*)d_in[0];
    const float* w = (const float*)d_in[1];
    const float* bias = (const float*)d_in[2];
    float* out = (float*)d_out;

    const int M = in_sizes[0] / K_DIM;  // 8192
    const int N = NF_DIM;               // 6400

    char* ws = (char*)d_ws;
    f16* qx = (f16*)ws;
    f16* wqt = (f16*)(ws + (size_t)M * KPAD * 2);
    float* ax = (float*)(ws + (size_t)M * KPAD * 2 + (size_t)N * KPAD * 2);
    float* sw = ax + M;

    quant_x_kernel<<<M, 256, 0, stream>>>(x, qx, ax);
    wscale_kernel<<<K_DIM, 256, 0, stream>>>(w, sw);
    wtq_kernel<<<dim3(KPAD / 64, NF_DIM / 64), 256, 0, stream>>>(w, sw, wqt);

    (void)hipFuncSetAttribute((const void*)gemm128x320,
                              hipFuncAttributeMaxDynamicSharedMemorySize, 2 * BUFSZ);
    gemm128x320<<<(M / 128) * (N / 320), 512, 2 * BUFSZ, stream>>>(qx, wqt, ax, bias, out, M, N);
}

// Round 8
// 222.324 us; speedup vs baseline: 1.1464x; 1.1464x over previous
//
#include <hip/hip_runtime.h>
#include <stdint.h>

typedef _Float16 f16;
typedef _Float16 f16x4 __attribute__((ext_vector_type(4)));
typedef _Float16 f16x8 __attribute__((ext_vector_type(8)));
typedef float f32x4 __attribute__((ext_vector_type(4)));

#define K_DIM 1600
#define NF_DIM 6400
#define KPAD 1664   // 26 tiles of 64
#define NKT 26
#define KPB (KPAD * 2)  // row stride bytes = 3328

// GEMM geometry: BM=128, BN=320, BK=64 -> 64x20 = 1280 tiles = 5/CU exact.
#define BUFSZ 57344   // A 16KB + B 40KB
#define BOFF 16384    // B region offset within buffer

// ---------- async global->LDS 16B copy ----------
__device__ __forceinline__ void async_copy16(const void* g, void* l) {
    __builtin_amdgcn_global_load_lds(
        (const __attribute__((address_space(1))) void*)(uintptr_t)g,
        (__attribute__((address_space(3))) void*)(uint32_t)(uintptr_t)l,
        16, 0, 0);
}

// ---------- block-wide max (256 threads = 4 waves) ----------
__device__ __forceinline__ float blockMax(float v, float* sm) {
#pragma unroll
    for (int off = 32; off > 0; off >>= 1)
        v = fmaxf(v, __shfl_down(v, off, 64));
    int wid = threadIdx.x >> 6, lane = threadIdx.x & 63;
    if (lane == 0) sm[wid] = v;
    __syncthreads();
    if (threadIdx.x == 0) {
        float m = sm[0];
        for (int i = 1; i < (int)(blockDim.x >> 6); ++i) m = fmaxf(m, sm[i]);
        sm[0] = m;
    }
    __syncthreads();
    return sm[0];
}

// ---------- per-token activation quant ----------
__global__ void quant_x_kernel(const float* __restrict__ x, f16* __restrict__ qx,
                               float* __restrict__ ax) {
    __shared__ float sm[4];
    size_t row = blockIdx.x;
    const float* xr = x + row * (size_t)K_DIM;
    float m = 0.f;
    const int n4 = K_DIM >> 2;
    for (int i = threadIdx.x; i < n4; i += blockDim.x) {
        float4 v = ((const float4*)xr)[i];
        m = fmaxf(fmaxf(fmaxf(fabsf(v.x), fabsf(v.y)), fmaxf(fabsf(v.z), fabsf(v.w))), m);
    }
    m = blockMax(m, sm);
    float s = 127.0f / (m + 1e-6f);
    if (threadIdx.x == 0) ax[row] = 1.0f / (s + 1e-6f);
    f16* qr = qx + row * (size_t)KPAD;
    for (int i = threadIdx.x; i < n4; i += blockDim.x) {
        float4 v = ((const float4*)xr)[i];
        f16x4 q;
        q[0] = (f16)rintf(v.x * s);
        q[1] = (f16)rintf(v.y * s);
        q[2] = (f16)rintf(v.z * s);
        q[3] = (f16)rintf(v.w * s);
        *(f16x4*)&qr[i * 4] = q;
    }
    if (threadIdx.x < 16) {
        f16x4 z = {};
        *(f16x4*)&qr[K_DIM + threadIdx.x * 4] = z;
    }
}

// ---------- per-row weight scale ----------
__global__ void wscale_kernel(const float* __restrict__ w, float* __restrict__ sw) {
    __shared__ float sm[4];
    size_t k = blockIdx.x;
    const float* wr = w + k * (size_t)NF_DIM;
    float m = 0.f;
    const int n4 = NF_DIM >> 2;
    for (int i = threadIdx.x; i < n4; i += blockDim.x) {
        float4 v = ((const float4*)wr)[i];
        m = fmaxf(fmaxf(fmaxf(fabsf(v.x), fabsf(v.y)), fmaxf(fabsf(v.z), fabsf(v.w))), m);
    }
    m = blockMax(m, sm);
    if (threadIdx.x == 0) sw[k] = 127.0f / (m + 1e-6f);
}

// ---------- quantize + transpose weight -> wqt[N][KPAD] fp16 ----------
__global__ void wtq_kernel(const float* __restrict__ w, const float* __restrict__ sw,
                           f16* __restrict__ wqt) {
    __shared__ f16 t[64][80];
    int k0 = blockIdx.x * 64;
    int f0 = blockIdx.y * 64;
    int tid = threadIdx.x;
    if (k0 >= K_DIM) {
        int fr = tid >> 2;
        int ch = (tid & 3) << 4;
        float4 z = {};
        float4* dst = (float4*)&wqt[(size_t)(f0 + fr) * KPAD + k0 + ch];
        dst[0] = z;
        dst[1] = z;
        return;
    }
    int rr = tid >> 4;
    int cc = (tid & 15) << 2;
#pragma unroll
    for (int i = 0; i < 4; ++i) {
        int r = rr + i * 16;
        float s = sw[k0 + r];
        float inv = 1.0f / (s + 1e-6f);
        float4 v = *(const float4*)&w[(size_t)(k0 + r) * NF_DIM + f0 + cc];
        t[cc + 0][r] = (f16)(rintf(v.x * s) * inv);
        t[cc + 1][r] = (f16)(rintf(v.y * s) * inv);
        t[cc + 2][r] = (f16)(rintf(v.z * s) * inv);
        t[cc + 3][r] = (f16)(rintf(v.w * s) * inv);
    }
    __syncthreads();
    int fr = tid >> 2;
    int ch = (tid & 3) << 4;
    const float4* src = (const float4*)&t[fr][ch];
    float4* dst = (float4*)&wqt[(size_t)(f0 + fr) * KPAD + k0 + ch];
    dst[0] = src[0];
    dst[1] = src[1];
}

// ---------- 128x320 GEMM: 4 phases/tile, 2 barriers/tile, fully counted waits ----------
__global__ __launch_bounds__(512, 1) void gemm128x320(
    const f16* __restrict__ A,    // [M][KPAD]
    const f16* __restrict__ Bt,   // [N][KPAD]
    const float* __restrict__ ax,
    const float* __restrict__ bias,
    float* __restrict__ C, int M, int N) {
    extern __shared__ char lds[];
    // buf b at lds + b*BUFSZ: A[128][64]f16 @+0, B[320][64]f16 @+16384

    const int tid = threadIdx.x;
    const int lane = tid & 63;
    const int wv = tid >> 6;   // 0..7
    const int wm = wv >> 2;    // 0..1 (64-row half)
    const int wn = wv & 3;     // 0..3 (80-col quarter)
    const int lr = lane & 15;
    const int lg = lane >> 4;

    const int bid = blockIdx.x;
    const int cpx = gridDim.x >> 3;     // 160 (1280 % 8 == 0 -> bijective)
    const int swz = (bid & 7) * cpx + (bid >> 3);
    const int tm = swz & 63;            // tn-major: consecutive swz share B panel
    const int tn = swz >> 6;
    const size_t m0 = (size_t)tm * 128, n0 = (size_t)tn * 320;

    // ---- staging pointers (inverse-swizzled source, linear LDS dest) ----
    const int srow8 = lane >> 3;
    const int sslot = (lane & 7) ^ srow8;
    const char* pA = (const char*)A + (m0 + (size_t)(wv * 8 + srow8)) * KPB + sslot * 16;
    const char* pB = (const char*)Bt + (n0 + (size_t)(wv * 8 + srow8)) * KPB + sslot * 16;
    const int L0 = wv * 1024 + lane * 16;

    // A tile: 2 loads/thread (rows 0-63, 64-127); B tile: 5 loads/thread
#define ST_A(bufo, t)                                                          \
    {                                                                          \
        const char* g_ = pA + (size_t)(t) * 128;                               \
        async_copy16(g_, lds + (bufo) + L0);                                   \
        async_copy16(g_ + (size_t)64 * KPB, lds + (bufo) + 8192 + L0);         \
    }
#define ST_B(bufo, t)                                                          \
    {                                                                          \
        const char* g_ = pB + (size_t)(t) * 128;                               \
        _Pragma("unroll") for (int c_ = 0; c_ < 5; ++c_)                       \
            async_copy16(g_ + (size_t)(c_ * 64) * KPB,                         \
                         lds + (bufo) + BOFF + c_ * 8192 + L0);                \
    }

    // ---- fragment-read constants (XOR swizzle folded per-thread) ----
    const int swz0 = ((lg) ^ (lr & 7)) << 4;       // kk=0 chunk
    const int swz1 = ((4 + lg) ^ (lr & 7)) << 4;   // kk=1 chunk
    const int rbA = (wm * 64 + lr) * 128;
    const int rbB = BOFF + wn * 10240 + lr * 128;

    // A piece: 2 frags (rows +0,+16); rowoff 0 = rows 0-31 of wave half, 4096 = rows 32-63
#define RD_A(dst, bufo, rowoff, sz)                                    \
    {                                                                  \
        const char* p_ = lds + (bufo) + rbA + (rowoff) + (sz);         \
        dst[0] = *(const f16x8*)(p_);                                  \
        dst[1] = *(const f16x8*)(p_ + 2048);                           \
    }
    // B set of one kk: 5 frags
#define RD_B(dst, bufo, sz)                                            \
    {                                                                  \
        const char* p_ = lds + (bufo) + rbB + (sz);                    \
        _Pragma("unroll") for (int n_ = 0; n_ < 5; ++n_)               \
            dst[n_] = *(const f16x8*)(p_ + n_ * 2048);                 \
    }

#define BARRIER __builtin_amdgcn_s_barrier()
#define LGKM(n) asm volatile("s_waitcnt lgkmcnt(" #n ")" ::: "memory")
#define VM5 asm volatile("s_waitcnt vmcnt(5)" ::: "memory")
#define SB0 __builtin_amdgcn_sched_barrier(0)

    // 10 MFMA: A piece (2 frags) x 5 B frags
#define MF25(AF, BF, R0)                                                          \
    {                                                                             \
        __builtin_amdgcn_s_setprio(1);                                            \
        _Pragma("unroll") for (int a_ = 0; a_ < 2; ++a_)                          \
        _Pragma("unroll") for (int n_ = 0; n_ < 5; ++n_)                          \
            acc[(R0) + a_][n_] = __builtin_amdgcn_mfma_f32_16x16x32_f16(          \
                AF[a_], BF[n_], acc[(R0) + a_][n_], 0, 0, 0);                     \
        __builtin_amdgcn_s_setprio(0);                                            \
    }

    // One tile. Counted ledger (per-wave, FIFO):
    //   ds: enter with 7 (pre-reads) -> PH1 +7 w(7) -> PH2 +2 w(2) -> PH3 +2 w(2)
    //       -> PH4 w(0) then +7 pre-reads for next tile.
    //   vm: t+1's 7 issued last tile; PH3 +5 (B,t+2); PH4 VM5 retires t+1's 7
    //       (leaves t+2's B 5); after BARRIER#2 +2 (A,t+2) -> 7.
#define TILE(CUR, NXT, tn2)                                           \
    {                                                                 \
        /* PH1 */                                                     \
        RD_A(aN, CUR, 0, swz1);                                       \
        RD_B(B1, CUR, swz1);                                          \
        LGKM(7); SB0;                                                 \
        MF25(aP, B0, 0);                                              \
        /* PH2 */                                                     \
        RD_A(aP, CUR, 4096, swz0);                                    \
        LGKM(2); SB0;                                                 \
        MF25(aN, B1, 0);                                              \
        BARRIER;            /* #1: all waves' CUR.B reads retired */  \
        /* PH3: stage B(t+2) into freed CUR.B */                      \
        ST_B(CUR, tn2);                                               \
        RD_A(aN, CUR, 4096, swz1);                                    \
        LGKM(2); SB0;                                                 \
        MF25(aP, B0, 2);                                              \
        /* PH4 */                                                     \
        LGKM(0);            /* retire last CUR.A reads (cheap) */     \
        VM5; SB0;           /* counted: t+1 landed, t+2.B in flight */\
        BARRIER;            /* #2: NXT complete, CUR.A free */        \
        ST_A(CUR, tn2);                                               \
        RD_A(aP, NXT, 0, swz0);                                       \
        RD_B(B0, NXT, swz0);                                          \
        SB0;                                                          \
        MF25(aN, B1, 2);                                              \
    }

    f32x4 acc[4][5] = {};
    f16x8 aP[2], aN[2], B0[5], B1[5];

    // ---- prologue: stage t0 + t1; counted wait for t0; pre-read t0 ----
    ST_A(0, 0);
    ST_B(0, 0);
    ST_A(BUFSZ, 1);
    ST_B(BUFSZ, 1);
    asm volatile("s_waitcnt vmcnt(7)" ::: "memory");  // t0's 7 landed; t1's in flight
    BARRIER;
    RD_A(aP, 0, 0, swz0);   // A rows +0,+16 k0 (t0)
    RD_B(B0, 0, swz0);      // B k0 (t0) -> 7 ds outstanding

    for (int i = 0; i < NKT; i += 2) {
        const int ta = (i + 2 < NKT) ? i + 2 : NKT - 1;  // clamped: rewrites freed regions only
        const int tb = (i + 3 < NKT) ? i + 3 : NKT - 1;
        TILE(0, BUFSZ, ta);
        TILE(BUFSZ, 0, tb);
    }
    asm volatile("s_waitcnt vmcnt(0) lgkmcnt(0)" ::: "memory");

    // ---- epilogue: direct stores, ax*acc + bias ----
    float bv[5];
#pragma unroll
    for (int n_ = 0; n_ < 5; ++n_) bv[n_] = bias[n0 + wn * 80 + n_ * 16 + lr];
#pragma unroll
    for (int a = 0; a < 4; ++a) {
#pragma unroll
        for (int j = 0; j < 4; ++j) {
            size_t row = m0 + wm * 64 + a * 16 + lg * 4 + j;
            float axv = ax[row];
            float* crow = C + row * (size_t)N + n0 + wn * 80;
#pragma unroll
            for (int n_ = 0; n_ < 5; ++n_)
                crow[n_ * 16 + lr] = acc[a][n_][j] * axv + bv[n_];
        }
    }
}

extern "C" void kernel_launch(void* const* d_in, const int* in_sizes, int n_in,
                              void* d_out, int out_size, void* d_ws, size_t ws_size,
                              hipStream_t stream) {
    const float* x = (const float*)d_in[0];
    const float* w = (const float*)d_in[1];
    const float* bias = (const float*)d_in[2];
    float* out = (float*)d_out;

    const int M = in_sizes[0] / K_DIM;  // 8192
    const int N = NF_DIM;               // 6400

    char* ws = (char*)d_ws;
    f16* qx = (f16*)ws;
    f16* wqt = (f16*)(ws + (size_t)M * KPAD * 2);
    float* ax = (float*)(ws + (size_t)M * KPAD * 2 + (size_t)N * KPAD * 2);
    float* sw = ax + M;

    quant_x_kernel<<<M, 256, 0, stream>>>(x, qx, ax);
    wscale_kernel<<<K_DIM, 256, 0, stream>>>(w, sw);
    wtq_kernel<<<dim3(KPAD / 64, NF_DIM / 64), 256, 0, stream>>>(w, sw, wqt);

    (void)hipFuncSetAttribute((const void*)gemm128x320,
                              hipFuncAttributeMaxDynamicSharedMemorySize, 2 * BUFSZ);
    gemm128x320<<<(M / 128) * (N / 320), 512, 2 * BUFSZ, stream>>>(qx, wqt, ax, bias, out, M, N);
}